// Round 4
// baseline (642.942 us; speedup 1.0000x reference)
//
#include <hip/hip_runtime.h>

#define NBLK_EDGE 1024         // blocks for hist/reorder; chunking must match
#define CHUNKE 7936            // max edges per reorder block (chunk = 7813)
#define BIN_SHIFT 10
#define BIN_SIZE 1024          // nodes per bin
#define NKEY 2048              // sort keys: (bin<<2)|quarter; K4 = 4*489 = 1956
#define ROW_BITS 19            // N=500,000 < 2^19
#define ROW_MASK ((1u << ROW_BITS) - 1)
#define Q_SHIFT 17             // source quarter = row>>17 (131072 nodes = 2MB of g0, per-XCD L2 resident)

typedef _Float16 half8  __attribute__((ext_vector_type(8)));
typedef _Float16 half2v __attribute__((ext_vector_type(2)));

// ---- shfl-based scans ------------------------------------------------------
__device__ __forceinline__ int wave_scan_incl(int v, int lane) {
#pragma unroll
    for (int d = 1; d < 64; d <<= 1) {
        int u = __shfl_up(v, d, 64);
        if (lane >= d) v += u;
    }
    return v;
}

// block-wide exclusive scan over 1024 per-thread values; wsum = __shared__ int[16]
__device__ __forceinline__ int block_excl_scan_1024(int v, int tid, int* wsum) {
    int lane = tid & 63, wv = tid >> 6;
    int incl = wave_scan_incl(v, lane);
    if (lane == 63) wsum[wv] = incl;
    __syncthreads();
    if (tid < 16) {
        int w = wsum[tid];
#pragma unroll
        for (int d = 1; d < 16; d <<= 1) {
            int u = __shfl_up(w, d, 16);
            if (tid >= d) w += u;
        }
        wsum[tid] = w;
    }
    __syncthreads();
    return incl - v + (wv ? wsum[wv - 1] : 0);
}

// Per-block LDS histogram of key=(col>>10)<<2 | row>>17. Persists per-block
// rows in both layouts: cntB (block-major) and cntT (key-major).
__global__ void __launch_bounds__(1024) k_hist(
        const int* __restrict__ row, const int* __restrict__ col,
        int E, int chunk, int* __restrict__ cntB, int* __restrict__ cntT) {
    __shared__ int lh[NKEY];
    int blk = blockIdx.x, tid = threadIdx.x;
    lh[tid] = 0;
    lh[tid + 1024] = 0;
    __syncthreads();
    int s = blk * chunk, e_ = min(s + chunk, E);
    for (int e = s + tid; e < e_; e += 1024) {
        unsigned key = ((unsigned)(col[e] >> BIN_SHIFT) << 2) | ((unsigned)row[e] >> Q_SHIFT);
        atomicAdd(&lh[key], 1);
    }
    __syncthreads();
    for (int k = tid; k < NKEY; k += 1024) {
        int v = lh[k];
        cntB[(size_t)blk * NKEY + k] = v;
        cntT[(size_t)k * NBLK_EDGE + blk] = v;
    }
}

// Per-key exclusive scan over the NBLK_EDGE per-block counts (in-place) and
// per-key total -> ghist. One block per key, 4 elements/thread (1024 = 256*4).
__global__ void k_colscan(int* __restrict__ cntT, int* __restrict__ ghist) {
    __shared__ int part[256];
    int b = blockIdx.x, tid = threadIdx.x;
    size_t base = (size_t)b * NBLK_EDGE;
    int t4 = tid * 4;
    int c0 = cntT[base + t4], c1 = cntT[base + t4 + 1],
        c2 = cntT[base + t4 + 2], c3 = cntT[base + t4 + 3];
    int sum = c0 + c1 + c2 + c3;
    part[tid] = sum;
    __syncthreads();
    for (int off = 1; off < 256; off <<= 1) {
        int v = (tid >= off) ? part[tid - off] : 0;
        __syncthreads();
        part[tid] += v;
        __syncthreads();
    }
    int excl = part[tid] - sum;
    cntT[base + t4]     = excl;
    cntT[base + t4 + 1] = excl + c0;
    cntT[base + t4 + 2] = excl + c0 + c1;
    cntT[base + t4 + 3] = excl + c0 + c1 + c2;
    if (tid == 255) ghist[b] = part[255];  // key total
}

// Exclusive scan over K4<=NKEY keys (single block, 2 keys/thread).
// Keys >= K4 have zero counts so their binBase == E (harmless).
__global__ void k_scan(const int* __restrict__ ghist, int K4, int* __restrict__ binBase) {
    __shared__ int wsum[16];
    int tid = threadIdx.x;
    int t2 = tid * 2;
    int v0 = (t2 < K4) ? ghist[t2] : 0;
    int v1 = (t2 + 1 < K4) ? ghist[t2 + 1] : 0;
    int excl = block_excl_scan_1024(v0 + v1, tid, wsum);
    if (t2 < NKEY) binBase[t2] = excl;
    if (t2 + 1 < NKEY) binBase[t2 + 1] = excl + v0;
    if (tid == 1023) binBase[NKEY] = excl + v0 + v1;  // == E
}

// Reorder with LOCAL SORT by (bin,quarter): place the chunk key-sorted in LDS,
// write out in contiguous per-key runs. ~71KB LDS -> 2 blocks/CU.
__global__ void __launch_bounds__(1024) k_reorder(
        const int* __restrict__ row, const int* __restrict__ col,
        int E, int chunk,
        const int* __restrict__ binBase, const int* __restrict__ cntB,
        const int* __restrict__ cntT, unsigned* __restrict__ packed) {
    __shared__ unsigned sorted[CHUNKE];       // 31 KB
    __shared__ unsigned short sbin[CHUNKE];   // 15.5 KB
    __shared__ int lcur[NKEY], lbase[NKEY], gbase[NKEY];  // 24 KB
    __shared__ int wsum[16];
    int blk = blockIdx.x, tid = threadIdx.x;
    int s = blk * chunk, e_ = min(s + chunk, E), len = e_ - s;
    size_t bb = (size_t)blk * NKEY;
    int t2 = tid * 2;
    int c0 = cntB[bb + t2], c1 = cntB[bb + t2 + 1];
    int excl = block_excl_scan_1024(c0 + c1, tid, wsum);
    lbase[t2] = excl;          lcur[t2] = excl;
    lbase[t2 + 1] = excl + c0; lcur[t2 + 1] = excl + c0;
    gbase[t2]     = binBase[t2]     + cntT[(size_t)t2 * NBLK_EDGE + blk];
    gbase[t2 + 1] = binBase[t2 + 1] + cntT[(size_t)(t2 + 1) * NBLK_EDGE + blk];
    __syncthreads();
    // placement: key-sorted staging in LDS (1 LDS atomic per edge)
    for (int i = tid; i < len; i += blockDim.x) {
        int cc = col[s + i], rr = row[s + i];
        unsigned key = ((unsigned)(cc >> BIN_SHIFT) << 2) | ((unsigned)rr >> Q_SHIFT);
        int slot = atomicAdd(&lcur[key], 1);
        sorted[slot] = ((unsigned)(cc & (BIN_SIZE - 1)) << ROW_BITS) | (unsigned)rr;
        sbin[slot] = (unsigned short)key;
    }
    __syncthreads();
    // coalesced run write-out
    for (int i = tid; i < len; i += blockDim.x) {
        int b = sbin[i];
        packed[gbase[b] + (i - lbase[b])] = sorted[i];
    }
}

// Per-bin degree count (1 LDS int atomic/edge) -> dinv, fused with the
// layer-1 MLP: g0 = f16(dinv * (x @ W1)).
__global__ void __launch_bounds__(1024) k_degmlp(
        const unsigned* __restrict__ packed, const int* __restrict__ binBase,
        const float* __restrict__ x, const float* __restrict__ W1,
        float* __restrict__ dinv, half8* __restrict__ g0, int N) {
    __shared__ int cnt[BIN_SIZE];
    __shared__ float w1s[128];
    int tid = threadIdx.x, bin = blockIdx.x;
    cnt[tid] = 0;
    if (tid < 128) w1s[tid] = W1[tid];
    __syncthreads();
    int s = binBase[bin << 2], t = binBase[(bin << 2) + 4];
    int sa = min((s + 3) & ~3, t);
    int tb = sa + ((t - sa) & ~3);
    for (int i = s + tid; i < sa; i += 1024) atomicAdd(&cnt[packed[i] >> ROW_BITS], 1);
    for (int ib = sa + tid * 4; ib < tb; ib += 4096) {
        uint4 v4 = *(const uint4*)(packed + ib);
        atomicAdd(&cnt[v4.x >> ROW_BITS], 1);
        atomicAdd(&cnt[v4.y >> ROW_BITS], 1);
        atomicAdd(&cnt[v4.z >> ROW_BITS], 1);
        atomicAdd(&cnt[v4.w >> ROW_BITS], 1);
    }
    for (int i = tb + tid; i < t; i += 1024) atomicAdd(&cnt[packed[i] >> ROW_BITS], 1);
    __syncthreads();
    int node = (bin << BIN_SHIFT) + tid;
    if (node < N) {
        float di = rsqrtf((float)(cnt[tid] + 1));  // +1 self-loop
        dinv[node] = di;
        const float4* xv = (const float4*)(x + (size_t)node * 16);
        float h[8];
#pragma unroll
        for (int j = 0; j < 8; ++j) h[j] = 0.0f;
#pragma unroll
        for (int kk = 0; kk < 4; ++kk) {
            float4 a = xv[kk];
            int kb = kk * 4;
#pragma unroll
            for (int j = 0; j < 8; ++j)
                h[j] += a.x * w1s[kb * 8 + j] + a.y * w1s[(kb + 1) * 8 + j]
                      + a.z * w1s[(kb + 2) * 8 + j] + a.w * w1s[(kb + 3) * 8 + j];
        }
        half8 g;
#pragma unroll
        for (int j = 0; j < 8; ++j) g[j] = (_Float16)(di * h[j]);
        g0[node] = g;
    }
}

// Layer-1 gather, edge-parallel per bin. Edges are quarter-sorted within the
// bin -> all resident blocks walk the same ~2MB g0 window (per-XCD L2 hit).
// uint4 packed loads give 4 outstanding gathers/thread. LDS f32 atomics into
// acc[j][node] ([j][node] layout -> bank = node%32, conflict-free).
__global__ void __launch_bounds__(1024) k_g1(
        const unsigned* __restrict__ packed, const int* __restrict__ binBase,
        const half8* __restrict__ g0, const float* __restrict__ dinv,
        const float* __restrict__ b1, const float* __restrict__ W2,
        half2v* __restrict__ g1, int N) {
    __shared__ float acc[8][BIN_SIZE];   // 32 KB
    int tid = threadIdx.x, bin = blockIdx.x;
#pragma unroll
    for (int j = 0; j < 8; ++j) acc[j][tid] = 0.0f;
    __syncthreads();
    int s = binBase[bin << 2], t = binBase[(bin << 2) + 4];
    int sa = min((s + 3) & ~3, t);
    int tb = sa + ((t - sa) & ~3);
    for (int i = s + tid; i < sa; i += 1024) {
        unsigned v = packed[i];
        int d = (int)(v >> ROW_BITS);
        half8 sv = g0[v & ROW_MASK];
#pragma unroll
        for (int j = 0; j < 8; ++j) atomicAdd(&acc[j][d], (float)sv[j]);
    }
    for (int ib = sa + tid * 4; ib < tb; ib += 4096) {
        uint4 v4 = *(const uint4*)(packed + ib);
        half8 s0 = g0[v4.x & ROW_MASK];
        half8 s1 = g0[v4.y & ROW_MASK];
        half8 s2 = g0[v4.z & ROW_MASK];
        half8 s3 = g0[v4.w & ROW_MASK];
        int d0 = (int)(v4.x >> ROW_BITS), d1 = (int)(v4.y >> ROW_BITS);
        int d2 = (int)(v4.z >> ROW_BITS), d3 = (int)(v4.w >> ROW_BITS);
#pragma unroll
        for (int j = 0; j < 8; ++j) {
            atomicAdd(&acc[j][d0], (float)s0[j]);
            atomicAdd(&acc[j][d1], (float)s1[j]);
            atomicAdd(&acc[j][d2], (float)s2[j]);
            atomicAdd(&acc[j][d3], (float)s3[j]);
        }
    }
    for (int i = tb + tid; i < t; i += 1024) {
        unsigned v = packed[i];
        int d = (int)(v >> ROW_BITS);
        half8 sv = g0[v & ROW_MASK];
#pragma unroll
        for (int j = 0; j < 8; ++j) atomicAdd(&acc[j][d], (float)sv[j]);
    }
    __syncthreads();
    int node = (bin << BIN_SHIFT) + tid;
    if (node < N) {
        float di = dinv[node];
        half8 self = g0[node];
        float o0 = 0.0f, o1 = 0.0f;
#pragma unroll
        for (int j = 0; j < 8; ++j) {
            float hj = fmaxf(di * (acc[j][tid] + (float)self[j]) + b1[j], 0.0f);
            o0 += hj * W2[j * 2 + 0];
            o1 += hj * W2[j * 2 + 1];
        }
        half2v g;
        g.x = (_Float16)(di * o0);
        g.y = (_Float16)(di * o1);
        g1[node] = g;
    }
}

// Layer-2 gather, edge-parallel per bin (g1 = 2MB, L2-resident everywhere),
// fused with log-softmax epilogue.
__global__ void __launch_bounds__(1024) k_g2(
        const unsigned* __restrict__ packed, const int* __restrict__ binBase,
        const half2v* __restrict__ g1, const float* __restrict__ dinv,
        const float* __restrict__ b2, float* __restrict__ out, int N) {
    __shared__ float acc0[BIN_SIZE], acc1[BIN_SIZE];   // 8 KB
    int tid = threadIdx.x, bin = blockIdx.x;
    acc0[tid] = 0.0f;
    acc1[tid] = 0.0f;
    __syncthreads();
    int s = binBase[bin << 2], t = binBase[(bin << 2) + 4];
    int sa = min((s + 3) & ~3, t);
    int tb = sa + ((t - sa) & ~3);
    for (int i = s + tid; i < sa; i += 1024) {
        unsigned v = packed[i];
        int d = (int)(v >> ROW_BITS);
        half2v sv = g1[v & ROW_MASK];
        atomicAdd(&acc0[d], (float)sv.x);
        atomicAdd(&acc1[d], (float)sv.y);
    }
    for (int ib = sa + tid * 4; ib < tb; ib += 4096) {
        uint4 v4 = *(const uint4*)(packed + ib);
        half2v s0 = g1[v4.x & ROW_MASK];
        half2v s1 = g1[v4.y & ROW_MASK];
        half2v s2 = g1[v4.z & ROW_MASK];
        half2v s3 = g1[v4.w & ROW_MASK];
        atomicAdd(&acc0[(int)(v4.x >> ROW_BITS)], (float)s0.x);
        atomicAdd(&acc1[(int)(v4.x >> ROW_BITS)], (float)s0.y);
        atomicAdd(&acc0[(int)(v4.y >> ROW_BITS)], (float)s1.x);
        atomicAdd(&acc1[(int)(v4.y >> ROW_BITS)], (float)s1.y);
        atomicAdd(&acc0[(int)(v4.z >> ROW_BITS)], (float)s2.x);
        atomicAdd(&acc1[(int)(v4.z >> ROW_BITS)], (float)s2.y);
        atomicAdd(&acc0[(int)(v4.w >> ROW_BITS)], (float)s3.x);
        atomicAdd(&acc1[(int)(v4.w >> ROW_BITS)], (float)s3.y);
    }
    for (int i = tb + tid; i < t; i += 1024) {
        unsigned v = packed[i];
        int d = (int)(v >> ROW_BITS);
        half2v sv = g1[v & ROW_MASK];
        atomicAdd(&acc0[d], (float)sv.x);
        atomicAdd(&acc1[d], (float)sv.y);
    }
    __syncthreads();
    int node = (bin << BIN_SHIFT) + tid;
    if (node < N) {
        float di = dinv[node];
        half2v self = g1[node];
        float o0 = di * (acc0[tid] + (float)self.x) + b2[0];
        float o1 = di * (acc1[tid] + (float)self.y) + b2[1];
        float m = fmaxf(o0, o1);
        float lse = m + logf(expf(o0 - m) + expf(o1 - m));
        ((float2*)out)[node] = make_float2(o0 - lse, o1 - lse);
    }
}

extern "C" void kernel_launch(void* const* d_in, const int* in_sizes, int n_in,
                              void* d_out, int out_size, void* d_ws, size_t ws_size,
                              hipStream_t stream) {
    const float* x  = (const float*)d_in[0];
    const float* W1 = (const float*)d_in[1];
    const float* b1 = (const float*)d_in[2];
    const float* W2 = (const float*)d_in[3];
    const float* b2 = (const float*)d_in[4];
    const int*   ei = (const int*)d_in[5];

    const int N = in_sizes[0] / 16;
    const int E = in_sizes[5] / 2;
    const int* row = ei;
    const int* col = ei + E;
    const int K = (N + BIN_SIZE - 1) >> BIN_SHIFT;  // 489 for N=500K
    const int K4 = K * 4;                           // 1956 sort keys

    float* ws   = (float*)d_ws;
    float* dinv = ws;                              // N floats
    half8* g0   = (half8*)(ws + (size_t)N);        // 4N floats worth
    half2v* g1  = (half2v*)(ws + (size_t)5 * N);   // N floats worth
    int*   meta = (int*)(ws + (size_t)6 * N);
    int* ghist      = meta;                        // NKEY ints
    int* binBase    = meta + NKEY;                 // NKEY+1 ints (padded)
    unsigned* packed = (unsigned*)(meta + 2 * NKEY + 64);     // E uints
    int* cntB = (int*)(packed + E);                // NKEY*NBLK_EDGE ints
    int* cntT = cntB + (size_t)NKEY * NBLK_EDGE;   // NKEY*NBLK_EDGE ints

    float* out = (float*)d_out;

    const int chunk = (E + NBLK_EDGE - 1) / NBLK_EDGE;  // 7813 <= CHUNKE

    k_hist   <<<NBLK_EDGE, 1024, 0, stream>>>(row, col, E, chunk, cntB, cntT);
    k_colscan<<<K4, 256, 0, stream>>>(cntT, ghist);
    k_scan   <<<1, 1024, 0, stream>>>(ghist, K4, binBase);
    k_reorder<<<NBLK_EDGE, 1024, 0, stream>>>(row, col, E, chunk,
                                              binBase, cntB, cntT, packed);
    k_degmlp <<<K, 1024, 0, stream>>>(packed, binBase, x, W1, dinv, g0, N);
    k_g1     <<<K, 1024, 0, stream>>>(packed, binBase, g0, dinv, b1, W2, g1, N);
    k_g2     <<<K, 1024, 0, stream>>>(packed, binBase, g1, dinv, b2, out, N);
}

// Round 5
// 351.234 us; speedup vs baseline: 1.8305x; 1.8305x over previous
//
#include <hip/hip_runtime.h>

#define TPB 256
#define NBLK_EDGE 512          // blocks for hist/reorder; chunking must match
#define CHUNKE 16384           // max edges per reorder block (chunk = 15625); 108KB LDS
#define BIN_SHIFT 9
#define BIN_SIZE 512           // nodes per bin
#define MAXK 1024              // max bins (N=500K -> K=977)
#define ROW_BITS 19            // N=500,000 < 2^19
#define ROW_MASK ((1u << ROW_BITS) - 1)
#define Q_SHIFT 17             // source quarter = row>>17 (131072 nodes = 2MB of g0, per-XCD L2)
#define NKEY 2048              // binsort keys: (local_node<<2)|quarter
#define CAP 12288              // binsort LDS buf2 capacity; mean bin = 8189 edges (+45 sigma)

typedef _Float16 half8  __attribute__((ext_vector_type(8)));
typedef _Float16 half2v __attribute__((ext_vector_type(2)));

// ---- shfl-based scans ------------------------------------------------------
__device__ __forceinline__ int wave_scan_incl(int v, int lane) {
#pragma unroll
    for (int d = 1; d < 64; d <<= 1) {
        int u = __shfl_up(v, d, 64);
        if (lane >= d) v += u;
    }
    return v;
}

// block-wide exclusive scan over 1024 per-thread values; wsum = __shared__ int[16]
__device__ __forceinline__ int block_excl_scan_1024(int v, int tid, int* wsum) {
    int lane = tid & 63, wv = tid >> 6;
    int incl = wave_scan_incl(v, lane);
    if (lane == 63) wsum[wv] = incl;
    __syncthreads();
    if (tid < 16) {
        int w = wsum[tid];
#pragma unroll
        for (int d = 1; d < 16; d <<= 1) {
            int u = __shfl_up(w, d, 16);
            if (tid >= d) w += u;
        }
        wsum[tid] = w;
    }
    __syncthreads();
    return incl - v + (wv ? wsum[wv - 1] : 0);
}

// Per-block LDS histogram of col>>BIN_SHIFT; persists per-block rows in both
// layouts: cntB (block-major, reload in k_reorder) and cntT (bin-major).
__global__ void __launch_bounds__(1024) k_hist(
        const int* __restrict__ col, int E, int chunk,
        int* __restrict__ cntB, int* __restrict__ cntT) {
    __shared__ int lh[MAXK];
    int blk = blockIdx.x, tid = threadIdx.x;
    lh[tid] = 0;
    __syncthreads();
    int s = blk * chunk, e_ = min(s + chunk, E);
    for (int e = s + tid; e < e_; e += 1024)
        atomicAdd(&lh[col[e] >> BIN_SHIFT], 1);
    __syncthreads();
    int v = lh[tid];
    cntB[(size_t)blk * MAXK + tid] = v;
    cntT[(size_t)tid * NBLK_EDGE + blk] = v;
}

// Per-bin exclusive scan over the NBLK_EDGE per-block counts (in-place) and
// per-bin total -> ghist. One block per bin, 2 elements/thread (512 = 256*2).
__global__ void k_colscan(int* __restrict__ cntT, int* __restrict__ ghist) {
    __shared__ int part[256];
    int b = blockIdx.x, tid = threadIdx.x;
    size_t base = (size_t)b * NBLK_EDGE;
    int t2 = tid * 2;
    int c0 = cntT[base + t2], c1 = cntT[base + t2 + 1];
    int sum = c0 + c1;
    part[tid] = sum;
    __syncthreads();
    for (int off = 1; off < 256; off <<= 1) {
        int v = (tid >= off) ? part[tid - off] : 0;
        __syncthreads();
        part[tid] += v;
        __syncthreads();
    }
    int excl = part[tid] - sum;
    cntT[base + t2]     = excl;
    cntT[base + t2 + 1] = excl + c0;
    if (tid == 255) ghist[b] = part[255];  // bin total
}

// Exclusive scan over K<=MAXK bins (single block of MAXK threads).
// Also zeroes the oversized-bin scratch ticket.
__global__ void __launch_bounds__(1024) k_scan(
        const int* __restrict__ ghist, int K, int* __restrict__ binBase,
        int* __restrict__ scratchCur) {
    __shared__ int wsum[16];
    int tid = threadIdx.x;
    if (tid == 0) *scratchCur = 0;
    int val = (tid < K) ? ghist[tid] : 0;
    int excl = block_excl_scan_1024(val, tid, wsum);
    binBase[tid] = excl;            // bins >= K get E (zero counts) - harmless
    if (tid == K - 1) binBase[K] = excl + val;  // == E
}

// Reorder with LOCAL SORT: place the block's 15.6K-edge chunk bin-sorted in
// LDS, then write out in contiguous per-bin runs (~16 edges = 64B full lines).
// 108KB LDS -> 1 block/CU (16 waves).
__global__ void __launch_bounds__(1024) k_reorder(
        const int* __restrict__ row, const int* __restrict__ col,
        int E, int chunk,
        const int* __restrict__ binBase, const int* __restrict__ cntB,
        const int* __restrict__ cntT, unsigned* __restrict__ packed) {
    __shared__ unsigned sorted[CHUNKE];       // 64 KB
    __shared__ unsigned short sbin[CHUNKE];   // 32 KB
    __shared__ int lcur[MAXK], lbase[MAXK], gbase[MAXK];  // 12 KB
    __shared__ int wsum[16];
    int blk = blockIdx.x, tid = threadIdx.x;
    int s = blk * chunk, e_ = min(s + chunk, E), len = e_ - s;
    size_t bb = (size_t)blk * MAXK;
    int c0 = cntB[bb + tid];
    int excl = block_excl_scan_1024(c0, tid, wsum);
    lbase[tid] = excl;
    lcur[tid] = excl;
    gbase[tid] = binBase[tid] + cntT[(size_t)tid * NBLK_EDGE + blk];
    __syncthreads();
    // placement: bin-sorted staging in LDS (1 LDS atomic per edge)
    for (int i = tid; i < len; i += blockDim.x) {
        int cc = col[s + i];
        int b = cc >> BIN_SHIFT;
        int slot = atomicAdd(&lcur[b], 1);
        sorted[slot] = ((unsigned)(cc & (BIN_SIZE - 1)) << ROW_BITS) | (unsigned)row[s + i];
        sbin[slot] = (unsigned short)b;
    }
    __syncthreads();
    // coalesced run write-out
    for (int i = tid; i < len; i += blockDim.x) {
        int b = sbin[i];
        packed[gbase[b] + (i - lbase[b])] = sorted[i];
    }
}

// Counting sort by composite key (local dest node, src quarter) within each
// bin -> keyptr (per-(node,quarter) segment bases). Placement into LDS buf2,
// final write-back LINEAR (coalesced). Oversized bins (>CAP) stage via global
// scratch (ticketed). FUSED TAIL: threads 0..511 compute
// g0 = f16(dinv * (x @ W1)) with degree already in-register.
__global__ void __launch_bounds__(1024) k_binsort(
        unsigned* __restrict__ packed, const int* __restrict__ binBase,
        unsigned* __restrict__ scratch, int* __restrict__ scratchCur,
        const float* __restrict__ x, const float* __restrict__ W1,
        half8* __restrict__ g0, int* __restrict__ keyptr, int N, int E, int K) {
    __shared__ unsigned buf2[CAP];     // 48 KB
    __shared__ int cnt[NKEY], cur[NKEY];   // 16 KB
    __shared__ float w1s[128];
    __shared__ int wsum[16];
    __shared__ int sbShared;
    int tid = threadIdx.x;
    int bin = blockIdx.x;
    int s = binBase[bin], t = binBase[bin + 1];
    int len = t - s;
    bool fast = (len <= CAP);
    cnt[tid] = 0;
    cnt[tid + 1024] = 0;
    if (tid < 128) w1s[tid] = W1[tid];
    if (!fast && tid == 0) sbShared = atomicAdd(scratchCur, len);
    __syncthreads();
    // pass 1: composite-key count (coalesced read, no staging)
    for (int i = tid; i < len; i += 1024) {
        unsigned v = packed[s + i];
        int k = (int)((v >> ROW_BITS) << 2) | (int)((v & ROW_MASK) >> Q_SHIFT);
        atomicAdd(&cnt[k], 1);
    }
    __syncthreads();
    // exclusive scan of cnt (2 keys/thread), cnt preserved
    int t2 = tid * 2;
    int c0 = cnt[t2], c1 = cnt[t2 + 1];
    int excl = block_excl_scan_1024(c0 + c1, tid, wsum);
    cur[t2] = excl;
    cur[t2 + 1] = excl + c0;
    int base = bin << BIN_SHIFT;
    // keyptr: per-(node,quarter) segment base; index (bin<<11)+k == 4*node+q
    if (base + (t2 >> 2) < N) keyptr[((size_t)bin << 11) + t2] = s + excl;
    if (base + ((t2 + 1) >> 2) < N) keyptr[((size_t)bin << 11) + t2 + 1] = s + excl + c0;
    float di = 0.0f;
    int node = base + tid;
    if (tid < BIN_SIZE && node < N) {
        int deg = cnt[4 * tid] + cnt[4 * tid + 1] + cnt[4 * tid + 2] + cnt[4 * tid + 3];
        di = rsqrtf((float)(deg + 1));  // +1 self-loop
    }
    if (bin == K - 1 && tid == 0) keyptr[(size_t)4 * N] = E;  // sentinel
    __syncthreads();
    if (fast) {
        // pass 2: re-read (L2-hot) -> place into LDS
        for (int i = tid; i < len; i += 1024) {
            unsigned v = packed[s + i];
            int k = (int)((v >> ROW_BITS) << 2) | (int)((v & ROW_MASK) >> Q_SHIFT);
            int slot = atomicAdd(&cur[k], 1);
            buf2[slot] = v;
        }
        __syncthreads();
        // coalesced linear write-back
        for (int i = tid; i < len; i += 1024) packed[s + i] = buf2[i];
    } else {
        unsigned* stg = scratch + sbShared;
        for (int i = tid; i < len; i += 1024) stg[i] = packed[s + i];
        __threadfence();
        __syncthreads();
        for (int i = tid; i < len; i += 1024) {
            unsigned v = stg[i];
            int k = (int)((v >> ROW_BITS) << 2) | (int)((v & ROW_MASK) >> Q_SHIFT);
            int slot = atomicAdd(&cur[k], 1);
            packed[s + slot] = v;
        }
    }
    // fused node1 tail: g0 = f16(dinv * (x @ W1)) for this bin's nodes
    if (tid < BIN_SIZE && node < N) {
        const float4* xv = (const float4*)(x + (size_t)node * 16);
        float h[8];
#pragma unroll
        for (int j = 0; j < 8; ++j) h[j] = 0.0f;
#pragma unroll
        for (int kk = 0; kk < 4; ++kk) {
            float4 a = xv[kk];
            int kb = kk * 4;
#pragma unroll
            for (int j = 0; j < 8; ++j)
                h[j] += a.x * w1s[kb * 8 + j] + a.y * w1s[(kb + 1) * 8 + j]
                      + a.z * w1s[(kb + 2) * 8 + j] + a.w * w1s[(kb + 3) * 8 + j];
        }
        half8 g;
#pragma unroll
        for (int j = 0; j < 8; ++j) g[j] = (_Float16)(di * h[j]);
        g0[node] = g;
    }
}

// Layer-1 gather, node-parallel, register accumulation (NO atomics, NO accA):
// quarter loop INSIDE the kernel with a block barrier per quarter. All ~1954
// blocks are co-resident -> loose global lockstep keeps each quarter's 2MB g0
// window per-XCD L2-resident. Epilogue: dinv from keyptr degree, relu MLP, g1.
__global__ void __launch_bounds__(TPB) k_gather1(
        const unsigned* __restrict__ packed, const int* __restrict__ keyptr,
        const half8* __restrict__ g0, const float* __restrict__ b1,
        const float* __restrict__ W2, half2v* __restrict__ g1, int N) {
    int i = blockIdx.x * blockDim.x + threadIdx.x;
    bool act = (i < N);
    int kp0 = 0, kp1 = 0, kp2 = 0, kp3 = 0, kp4 = 0;
    if (act) {
        int4 k4 = ((const int4*)keyptr)[i];
        kp0 = k4.x; kp1 = k4.y; kp2 = k4.z; kp3 = k4.w;
        kp4 = keyptr[4 * i + 4];
    }
    float acc[8];
#pragma unroll
    for (int j = 0; j < 8; ++j) acc[j] = 0.0f;
#pragma unroll
    for (int q = 0; q < 4; ++q) {
        int e = (q == 0) ? kp0 : (q == 1) ? kp1 : (q == 2) ? kp2 : kp3;
        int t = (q == 0) ? kp1 : (q == 1) ? kp2 : (q == 2) ? kp3 : kp4;
        if (act) {
            for (; e + 4 <= t; e += 4) {
                unsigned p0 = packed[e], p1 = packed[e + 1],
                         p2 = packed[e + 2], p3 = packed[e + 3];
                half8 v0 = g0[p0 & ROW_MASK];
                half8 v1 = g0[p1 & ROW_MASK];
                half8 v2 = g0[p2 & ROW_MASK];
                half8 v3 = g0[p3 & ROW_MASK];
#pragma unroll
                for (int j = 0; j < 8; ++j)
                    acc[j] += (float)v0[j] + (float)v1[j] + (float)v2[j] + (float)v3[j];
            }
            for (; e < t; ++e) {
                half8 v = g0[packed[e] & ROW_MASK];
#pragma unroll
                for (int j = 0; j < 8; ++j) acc[j] += (float)v[j];
            }
        }
        __syncthreads();   // quarter phase alignment (block-level, cheap)
    }
    if (act) {
        half8 self = g0[i];
        float di = rsqrtf((float)(kp4 - kp0 + 1));  // degree + self-loop
        float o0 = 0.0f, o1 = 0.0f;
#pragma unroll
        for (int j = 0; j < 8; ++j) {
            float hj = fmaxf(di * (acc[j] + (float)self[j]) + b1[j], 0.0f);
            o0 += hj * W2[j * 2 + 0];
            o1 += hj * W2[j * 2 + 1];
        }
        half2v g;
        g.x = (_Float16)(di * o0);
        g.y = (_Float16)(di * o1);
        g1[i] = g;
    }
}

// Layer-2 gather (g1 = 2MB, L2-resident everywhere) + log-softmax epilogue.
__global__ void __launch_bounds__(TPB) k_gather2(
        const unsigned* __restrict__ packed, const int* __restrict__ keyptr,
        const half2v* __restrict__ g1, const float* __restrict__ b2,
        float* __restrict__ out, int N) {
    int i = blockIdx.x * blockDim.x + threadIdx.x;
    if (i >= N) return;
    int s = keyptr[4 * i], t = keyptr[4 * i + 4];
    half2v sg = g1[i];
    float a0 = (float)sg.x, a1 = (float)sg.y;  // self-loop
    int e = s;
    for (; e + 4 <= t; e += 4) {
        unsigned p0 = packed[e], p1 = packed[e + 1], p2 = packed[e + 2], p3 = packed[e + 3];
        half2v v0 = g1[p0 & ROW_MASK];
        half2v v1 = g1[p1 & ROW_MASK];
        half2v v2 = g1[p2 & ROW_MASK];
        half2v v3 = g1[p3 & ROW_MASK];
        a0 += (float)v0.x + (float)v1.x + (float)v2.x + (float)v3.x;
        a1 += (float)v0.y + (float)v1.y + (float)v2.y + (float)v3.y;
    }
    for (; e < t; ++e) {
        half2v v = g1[packed[e] & ROW_MASK];
        a0 += (float)v.x;
        a1 += (float)v.y;
    }
    float di = rsqrtf((float)(t - s + 1));
    float o0 = di * a0 + b2[0];
    float o1 = di * a1 + b2[1];
    float m = fmaxf(o0, o1);
    float lse = m + logf(expf(o0 - m) + expf(o1 - m));
    ((float2*)out)[i] = make_float2(o0 - lse, o1 - lse);
}

extern "C" void kernel_launch(void* const* d_in, const int* in_sizes, int n_in,
                              void* d_out, int out_size, void* d_ws, size_t ws_size,
                              hipStream_t stream) {
    const float* x  = (const float*)d_in[0];
    const float* W1 = (const float*)d_in[1];
    const float* b1 = (const float*)d_in[2];
    const float* W2 = (const float*)d_in[3];
    const float* b2 = (const float*)d_in[4];
    const int*   ei = (const int*)d_in[5];

    const int N = in_sizes[0] / 16;
    const int E = in_sizes[5] / 2;
    const int* row = ei;
    const int* col = ei + E;
    const int K = (N + BIN_SIZE - 1) >> BIN_SHIFT;  // 977 for N=500K

    float* ws   = (float*)d_ws;
    half8* g0   = (half8*)ws;                      // 4N floats worth
    half2v* g1  = (half2v*)(ws + (size_t)4 * N);   // N floats worth
    unsigned* scratch = (unsigned*)(ws + (size_t)5 * N);  // 8N (oversized-bin staging)
    int* keyptr = (int*)(ws + (size_t)13 * N);     // 4N+1 ints (16B-aligned: 13N*4 % 16 == 0)
    int*   meta = (int*)(ws + (size_t)17 * N + 8);
    int* ghist      = meta;                        // MAXK ints
    int* binBase    = meta + MAXK;                 // MAXK+1 ints (padded)
    int* scratchCur = meta + 2 * MAXK + 16;        // 1 int
    unsigned* packed = (unsigned*)(meta + 3 * MAXK);          // E uints
    int* cntB = (int*)(packed + E);                // MAXK*NBLK_EDGE ints
    int* cntT = cntB + (size_t)MAXK * NBLK_EDGE;   // MAXK*NBLK_EDGE ints

    float* out = (float*)d_out;

    const int gN = (N + TPB - 1) / TPB;
    const int chunk = (E + NBLK_EDGE - 1) / NBLK_EDGE;  // 15625 <= CHUNKE

    k_hist   <<<NBLK_EDGE, 1024, 0, stream>>>(col, E, chunk, cntB, cntT);
    k_colscan<<<K, 256, 0, stream>>>(cntT, ghist);
    k_scan   <<<1, MAXK, 0, stream>>>(ghist, K, binBase, scratchCur);
    k_reorder<<<NBLK_EDGE, 1024, 0, stream>>>(row, col, E, chunk,
                                              binBase, cntB, cntT, packed);
    k_binsort<<<K, 1024, 0, stream>>>(packed, binBase, scratch, scratchCur,
                                      x, W1, g0, keyptr, N, E, K);
    k_gather1<<<gN, TPB, 0, stream>>>(packed, keyptr, g0, b1, W2, g1, N);
    k_gather2<<<gN, TPB, 0, stream>>>(packed, keyptr, g1, b2, out, N);
}

// Round 6
// 340.424 us; speedup vs baseline: 1.8886x; 1.0318x over previous
//
#include <hip/hip_runtime.h>

#define TPB 256
#define NBLK_EDGE 512          // blocks for hist/reorder; chunking must match
#define CHUNKE 16384           // max edges per reorder block (chunk = 15625); 108KB LDS
#define BIN_SHIFT 9
#define BIN_SIZE 512           // nodes per bin
#define MAXK 1024              // max bins (N=500K -> K=977)
#define ROW_BITS 19            // N=500,000 < 2^19
#define ROW_MASK ((1u << ROW_BITS) - 1)
#define Q_SHIFT 17             // source quarter = row>>17 (131072 nodes = 2MB of g0, per-XCD L2)
#define NKEY 2048              // binsort keys: (local_node<<2)|quarter
#define CAP 12288              // binsort LDS buf2 capacity; mean bin = 8189 edges (+45 sigma)
#define G1_TPB 512             // gather1: 512 thr, 1 node/thread, 4 blk/CU -> ALL blocks co-resident

typedef _Float16 half8  __attribute__((ext_vector_type(8)));
typedef _Float16 half2v __attribute__((ext_vector_type(2)));

// ---- shfl-based scans ------------------------------------------------------
__device__ __forceinline__ int wave_scan_incl(int v, int lane) {
#pragma unroll
    for (int d = 1; d < 64; d <<= 1) {
        int u = __shfl_up(v, d, 64);
        if (lane >= d) v += u;
    }
    return v;
}

// block-wide exclusive scan over 1024 per-thread values; wsum = __shared__ int[16]
__device__ __forceinline__ int block_excl_scan_1024(int v, int tid, int* wsum) {
    int lane = tid & 63, wv = tid >> 6;
    int incl = wave_scan_incl(v, lane);
    if (lane == 63) wsum[wv] = incl;
    __syncthreads();
    if (tid < 16) {
        int w = wsum[tid];
#pragma unroll
        for (int d = 1; d < 16; d <<= 1) {
            int u = __shfl_up(w, d, 16);
            if (tid >= d) w += u;
        }
        wsum[tid] = w;
    }
    __syncthreads();
    return incl - v + (wv ? wsum[wv - 1] : 0);
}

// Per-block LDS histogram of col>>BIN_SHIFT; persists per-block rows in both
// layouts: cntB (block-major, reload in k_reorder) and cntT (bin-major).
__global__ void __launch_bounds__(1024) k_hist(
        const int* __restrict__ col, int E, int chunk,
        int* __restrict__ cntB, int* __restrict__ cntT) {
    __shared__ int lh[MAXK];
    int blk = blockIdx.x, tid = threadIdx.x;
    lh[tid] = 0;
    __syncthreads();
    int s = blk * chunk, e_ = min(s + chunk, E);
    for (int e = s + tid; e < e_; e += 1024)
        atomicAdd(&lh[col[e] >> BIN_SHIFT], 1);
    __syncthreads();
    int v = lh[tid];
    cntB[(size_t)blk * MAXK + tid] = v;
    cntT[(size_t)tid * NBLK_EDGE + blk] = v;
}

// Per-bin exclusive scan over the NBLK_EDGE per-block counts (in-place) and
// per-bin total -> ghist. One block per bin, 2 elements/thread (512 = 256*2).
__global__ void k_colscan(int* __restrict__ cntT, int* __restrict__ ghist) {
    __shared__ int part[256];
    int b = blockIdx.x, tid = threadIdx.x;
    size_t base = (size_t)b * NBLK_EDGE;
    int t2 = tid * 2;
    int c0 = cntT[base + t2], c1 = cntT[base + t2 + 1];
    int sum = c0 + c1;
    part[tid] = sum;
    __syncthreads();
    for (int off = 1; off < 256; off <<= 1) {
        int v = (tid >= off) ? part[tid - off] : 0;
        __syncthreads();
        part[tid] += v;
        __syncthreads();
    }
    int excl = part[tid] - sum;
    cntT[base + t2]     = excl;
    cntT[base + t2 + 1] = excl + c0;
    if (tid == 255) ghist[b] = part[255];  // bin total
}

// Exclusive scan over K<=MAXK bins (single block of MAXK threads).
// Also zeroes the oversized-bin scratch ticket.
__global__ void __launch_bounds__(1024) k_scan(
        const int* __restrict__ ghist, int K, int* __restrict__ binBase,
        int* __restrict__ scratchCur) {
    __shared__ int wsum[16];
    int tid = threadIdx.x;
    if (tid == 0) *scratchCur = 0;
    int val = (tid < K) ? ghist[tid] : 0;
    int excl = block_excl_scan_1024(val, tid, wsum);
    binBase[tid] = excl;            // bins >= K get E (zero counts) - harmless
    if (tid == K - 1) binBase[K] = excl + val;  // == E
}

// Reorder with LOCAL SORT: place the block's 15.6K-edge chunk bin-sorted in
// LDS, then write out in contiguous per-bin runs (~16 edges = 64B full lines).
// 108KB LDS -> 1 block/CU (16 waves).
__global__ void __launch_bounds__(1024) k_reorder(
        const int* __restrict__ row, const int* __restrict__ col,
        int E, int chunk,
        const int* __restrict__ binBase, const int* __restrict__ cntB,
        const int* __restrict__ cntT, unsigned* __restrict__ packed) {
    __shared__ unsigned sorted[CHUNKE];       // 64 KB
    __shared__ unsigned short sbin[CHUNKE];   // 32 KB
    __shared__ int lcur[MAXK], lbase[MAXK], gbase[MAXK];  // 12 KB
    __shared__ int wsum[16];
    int blk = blockIdx.x, tid = threadIdx.x;
    int s = blk * chunk, e_ = min(s + chunk, E), len = e_ - s;
    size_t bb = (size_t)blk * MAXK;
    int c0 = cntB[bb + tid];
    int excl = block_excl_scan_1024(c0, tid, wsum);
    lbase[tid] = excl;
    lcur[tid] = excl;
    gbase[tid] = binBase[tid] + cntT[(size_t)tid * NBLK_EDGE + blk];
    __syncthreads();
    // placement: bin-sorted staging in LDS (1 LDS atomic per edge)
    for (int i = tid; i < len; i += blockDim.x) {
        int cc = col[s + i];
        int b = cc >> BIN_SHIFT;
        int slot = atomicAdd(&lcur[b], 1);
        sorted[slot] = ((unsigned)(cc & (BIN_SIZE - 1)) << ROW_BITS) | (unsigned)row[s + i];
        sbin[slot] = (unsigned short)b;
    }
    __syncthreads();
    // coalesced run write-out
    for (int i = tid; i < len; i += blockDim.x) {
        int b = sbin[i];
        packed[gbase[b] + (i - lbase[b])] = sorted[i];
    }
}

// Counting sort by composite key (local dest node, src quarter) within each
// bin -> keyptr (per-(node,quarter) segment bases). Placement into LDS buf2,
// final write-back LINEAR (coalesced). Oversized bins (>CAP) stage via global
// scratch (ticketed). FUSED TAIL: threads 0..511 compute
// g0 = f16(dinv * (x @ W1)) with degree already in-register.
__global__ void __launch_bounds__(1024) k_binsort(
        unsigned* __restrict__ packed, const int* __restrict__ binBase,
        unsigned* __restrict__ scratch, int* __restrict__ scratchCur,
        const float* __restrict__ x, const float* __restrict__ W1,
        half8* __restrict__ g0, int* __restrict__ keyptr, int N, int E, int K) {
    __shared__ unsigned buf2[CAP];     // 48 KB
    __shared__ int cnt[NKEY], cur[NKEY];   // 16 KB
    __shared__ float w1s[128];
    __shared__ int wsum[16];
    __shared__ int sbShared;
    int tid = threadIdx.x;
    int bin = blockIdx.x;
    int s = binBase[bin], t = binBase[bin + 1];
    int len = t - s;
    bool fast = (len <= CAP);
    cnt[tid] = 0;
    cnt[tid + 1024] = 0;
    if (tid < 128) w1s[tid] = W1[tid];
    if (!fast && tid == 0) sbShared = atomicAdd(scratchCur, len);
    __syncthreads();
    // pass 1: composite-key count (coalesced read, no staging)
    for (int i = tid; i < len; i += 1024) {
        unsigned v = packed[s + i];
        int k = (int)((v >> ROW_BITS) << 2) | (int)((v & ROW_MASK) >> Q_SHIFT);
        atomicAdd(&cnt[k], 1);
    }
    __syncthreads();
    // exclusive scan of cnt (2 keys/thread), cnt preserved
    int t2 = tid * 2;
    int c0 = cnt[t2], c1 = cnt[t2 + 1];
    int excl = block_excl_scan_1024(c0 + c1, tid, wsum);
    cur[t2] = excl;
    cur[t2 + 1] = excl + c0;
    int base = bin << BIN_SHIFT;
    // keyptr: per-(node,quarter) segment base; index (bin<<11)+k == 4*node+q
    if (base + (t2 >> 2) < N) keyptr[((size_t)bin << 11) + t2] = s + excl;
    if (base + ((t2 + 1) >> 2) < N) keyptr[((size_t)bin << 11) + t2 + 1] = s + excl + c0;
    float di = 0.0f;
    int node = base + tid;
    if (tid < BIN_SIZE && node < N) {
        int deg = cnt[4 * tid] + cnt[4 * tid + 1] + cnt[4 * tid + 2] + cnt[4 * tid + 3];
        di = rsqrtf((float)(deg + 1));  // +1 self-loop
    }
    if (bin == K - 1 && tid == 0) keyptr[(size_t)4 * N] = E;  // sentinel
    __syncthreads();
    if (fast) {
        // pass 2: re-read (L2-hot) -> place into LDS
        for (int i = tid; i < len; i += 1024) {
            unsigned v = packed[s + i];
            int k = (int)((v >> ROW_BITS) << 2) | (int)((v & ROW_MASK) >> Q_SHIFT);
            int slot = atomicAdd(&cur[k], 1);
            buf2[slot] = v;
        }
        __syncthreads();
        // coalesced linear write-back
        for (int i = tid; i < len; i += 1024) packed[s + i] = buf2[i];
    } else {
        unsigned* stg = scratch + sbShared;
        for (int i = tid; i < len; i += 1024) stg[i] = packed[s + i];
        __threadfence();
        __syncthreads();
        for (int i = tid; i < len; i += 1024) {
            unsigned v = stg[i];
            int k = (int)((v >> ROW_BITS) << 2) | (int)((v & ROW_MASK) >> Q_SHIFT);
            int slot = atomicAdd(&cur[k], 1);
            packed[s + slot] = v;
        }
    }
    // fused node1 tail: g0 = f16(dinv * (x @ W1)) for this bin's nodes
    if (tid < BIN_SIZE && node < N) {
        const float4* xv = (const float4*)(x + (size_t)node * 16);
        float h[8];
#pragma unroll
        for (int j = 0; j < 8; ++j) h[j] = 0.0f;
#pragma unroll
        for (int kk = 0; kk < 4; ++kk) {
            float4 a = xv[kk];
            int kb = kk * 4;
#pragma unroll
            for (int j = 0; j < 8; ++j)
                h[j] += a.x * w1s[kb * 8 + j] + a.y * w1s[(kb + 1) * 8 + j]
                      + a.z * w1s[(kb + 2) * 8 + j] + a.w * w1s[(kb + 3) * 8 + j];
        }
        half8 g;
#pragma unroll
        for (int j = 0; j < 8; ++j) g[j] = (_Float16)(di * h[j]);
        g0[node] = g;
    }
}

// Layer-1 gather, node-parallel, register accumulation, quarter-phased.
// CO-RESIDENCY IS THE POINT: 977 blocks x 512 thr at 4 blk/CU (launch_bounds
// caps VGPR<=64, zero LDS) -> the ENTIRE grid is resident from cycle 0, so
// every block enters quarter q together (barrier per quarter keeps it tight).
// One ~2MB g0 window live per XCD at a time -> L2-resident. Round-5's 1954
// non-resident blocks smeared phases across the launch tail (312MB FETCH).
__global__ void __launch_bounds__(G1_TPB, 8) k_gather1(
        const unsigned* __restrict__ packed, const int* __restrict__ keyptr,
        const half8* __restrict__ g0, const float* __restrict__ b1,
        const float* __restrict__ W2, half2v* __restrict__ g1, int N) {
    int i = blockIdx.x * G1_TPB + threadIdx.x;
    bool act = (i < N);
    int kp0 = 0, kp1 = 0, kp2 = 0, kp3 = 0, kp4 = 0;
    if (act) {
        int4 k4 = ((const int4*)keyptr)[i];
        kp0 = k4.x; kp1 = k4.y; kp2 = k4.z; kp3 = k4.w;
        kp4 = keyptr[4 * i + 4];
    }
    float acc[8];
#pragma unroll
    for (int j = 0; j < 8; ++j) acc[j] = 0.0f;
#pragma unroll
    for (int q = 0; q < 4; ++q) {
        int e = (q == 0) ? kp0 : (q == 1) ? kp1 : (q == 2) ? kp2 : kp3;
        int t = (q == 0) ? kp1 : (q == 1) ? kp2 : (q == 2) ? kp3 : kp4;
        if (act) {
            for (; e + 4 <= t; e += 4) {
                unsigned p0 = packed[e], p1 = packed[e + 1],
                         p2 = packed[e + 2], p3 = packed[e + 3];
                half8 v0 = g0[p0 & ROW_MASK];
                half8 v1 = g0[p1 & ROW_MASK];
                half8 v2 = g0[p2 & ROW_MASK];
                half8 v3 = g0[p3 & ROW_MASK];
#pragma unroll
                for (int j = 0; j < 8; ++j)
                    acc[j] += (float)v0[j] + (float)v1[j] + (float)v2[j] + (float)v3[j];
            }
            for (; e < t; ++e) {
                half8 v = g0[packed[e] & ROW_MASK];
#pragma unroll
                for (int j = 0; j < 8; ++j) acc[j] += (float)v[j];
            }
        }
        __syncthreads();   // quarter phase alignment
    }
    if (act) {
        half8 self = g0[i];
        float di = rsqrtf((float)(kp4 - kp0 + 1));  // degree + self-loop
        float o0 = 0.0f, o1 = 0.0f;
#pragma unroll
        for (int j = 0; j < 8; ++j) {
            float hj = fmaxf(di * (acc[j] + (float)self[j]) + b1[j], 0.0f);
            o0 += hj * W2[j * 2 + 0];
            o1 += hj * W2[j * 2 + 1];
        }
        half2v g;
        g.x = (_Float16)(di * o0);
        g.y = (_Float16)(di * o1);
        g1[i] = g;
    }
}

// Layer-2 gather (g1 = 2MB, per-XCD L2-resident) + log-softmax epilogue.
__global__ void __launch_bounds__(TPB) k_gather2(
        const unsigned* __restrict__ packed, const int* __restrict__ keyptr,
        const half2v* __restrict__ g1, const float* __restrict__ b2,
        float* __restrict__ out, int N) {
    int i = blockIdx.x * blockDim.x + threadIdx.x;
    if (i >= N) return;
    int s = keyptr[4 * i], t = keyptr[4 * i + 4];
    half2v sg = g1[i];
    float a0 = (float)sg.x, a1 = (float)sg.y;  // self-loop
    int e = s;
    for (; e + 4 <= t; e += 4) {
        unsigned p0 = packed[e], p1 = packed[e + 1], p2 = packed[e + 2], p3 = packed[e + 3];
        half2v v0 = g1[p0 & ROW_MASK];
        half2v v1 = g1[p1 & ROW_MASK];
        half2v v2 = g1[p2 & ROW_MASK];
        half2v v3 = g1[p3 & ROW_MASK];
        a0 += (float)v0.x + (float)v1.x + (float)v2.x + (float)v3.x;
        a1 += (float)v0.y + (float)v1.y + (float)v2.y + (float)v3.y;
    }
    for (; e < t; ++e) {
        half2v v = g1[packed[e] & ROW_MASK];
        a0 += (float)v.x;
        a1 += (float)v.y;
    }
    float di = rsqrtf((float)(t - s + 1));
    float o0 = di * a0 + b2[0];
    float o1 = di * a1 + b2[1];
    float m = fmaxf(o0, o1);
    float lse = m + logf(expf(o0 - m) + expf(o1 - m));
    ((float2*)out)[i] = make_float2(o0 - lse, o1 - lse);
}

extern "C" void kernel_launch(void* const* d_in, const int* in_sizes, int n_in,
                              void* d_out, int out_size, void* d_ws, size_t ws_size,
                              hipStream_t stream) {
    const float* x  = (const float*)d_in[0];
    const float* W1 = (const float*)d_in[1];
    const float* b1 = (const float*)d_in[2];
    const float* W2 = (const float*)d_in[3];
    const float* b2 = (const float*)d_in[4];
    const int*   ei = (const int*)d_in[5];

    const int N = in_sizes[0] / 16;
    const int E = in_sizes[5] / 2;
    const int* row = ei;
    const int* col = ei + E;
    const int K = (N + BIN_SIZE - 1) >> BIN_SHIFT;  // 977 for N=500K

    float* ws   = (float*)d_ws;
    half8* g0   = (half8*)ws;                      // 4N floats worth
    half2v* g1  = (half2v*)(ws + (size_t)4 * N);   // N floats worth
    unsigned* scratch = (unsigned*)(ws + (size_t)5 * N);  // 8N (oversized-bin staging)
    int* keyptr = (int*)(ws + (size_t)13 * N);     // 4N+1 ints (16B-aligned)
    int*   meta = (int*)(ws + (size_t)17 * N + 8);
    int* ghist      = meta;                        // MAXK ints
    int* binBase    = meta + MAXK;                 // MAXK+1 ints (padded)
    int* scratchCur = meta + 2 * MAXK + 16;        // 1 int
    unsigned* packed = (unsigned*)(meta + 3 * MAXK);          // E uints
    int* cntB = (int*)(packed + E);                // MAXK*NBLK_EDGE ints
    int* cntT = cntB + (size_t)MAXK * NBLK_EDGE;   // MAXK*NBLK_EDGE ints

    float* out = (float*)d_out;

    const int gN = (N + TPB - 1) / TPB;
    const int g1N = (N + G1_TPB - 1) / G1_TPB;          // 977 blocks: all co-resident
    const int chunk = (E + NBLK_EDGE - 1) / NBLK_EDGE;  // 15625 <= CHUNKE

    k_hist   <<<NBLK_EDGE, 1024, 0, stream>>>(col, E, chunk, cntB, cntT);
    k_colscan<<<K, 256, 0, stream>>>(cntT, ghist);
    k_scan   <<<1, MAXK, 0, stream>>>(ghist, K, binBase, scratchCur);
    k_reorder<<<NBLK_EDGE, 1024, 0, stream>>>(row, col, E, chunk,
                                              binBase, cntB, cntT, packed);
    k_binsort<<<K, 1024, 0, stream>>>(packed, binBase, scratch, scratchCur,
                                      x, W1, g0, keyptr, N, E, K);
    k_gather1<<<g1N, G1_TPB, 0, stream>>>(packed, keyptr, g0, b1, W2, g1, N);
    k_gather2<<<gN, TPB, 0, stream>>>(packed, keyptr, g1, b2, out, N);
}